// Round 6
// baseline (211.251 us; speedup 1.0000x reference)
//
#include <hip/hip_runtime.h>

constexpr int BLK = 256;

// Compiler-proof IEEE f32 rn ops (inline asm: no fusion/reassociation
// beyond what is written).
__device__ __forceinline__ float mul_rn(float a, float b) {
    float r; asm("v_mul_f32 %0, %1, %2" : "=v"(r) : "v"(a), "v"(b)); return r;
}
__device__ __forceinline__ float add_rn(float a, float b) {
    float r; asm("v_add_f32 %0, %1, %2" : "=v"(r) : "v"(a), "v"(b)); return r;
}
__device__ __forceinline__ float sub_rn(float a, float b) {
    float r; asm("v_sub_f32 %0, %1, %2" : "=v"(r) : "v"(a), "v"(b)); return r;
}
__device__ __forceinline__ float fma_rn(float a, float b, float c) {
    float r; asm("v_fma_f32 %0, %1, %2, %3"
                 : "=v"(r) : "v"(a), "v"(b), "v"(c)); return r;
}

// Ascending FMA chain from zero — matches the np/XLA-lowered dot rounding:
//   fma(a2,b2, fma(a1,b1, rn(a0*b0)))
// Do not reassociate; do not let the compiler contract it differently.
__device__ __forceinline__ float dot3_fma_asc(float a0, float a1, float a2,
                                              float b0, float b1, float b2) {
    return fma_rn(a2, b2, fma_rn(a1, b1, mul_rn(a0, b0)));
}

// Full per-element pipeline — the precision-critical chain, verbatim from
// the passing kernels (absmax 0.0625). E,T,R point at 9 floats each; all
// call sites use compile-time-constant offsets so SROA keeps everything
// in registers.
__device__ __forceinline__ float so3_nll_elem(const float* E, const float* T,
                                              const float* R) {
    // ---- chaotic chain: must match the np ref's f32 rounding ----
    float d00 = dot3_fma_asc(E[0],E[1],E[2], T[0],T[1],T[2]);
    float d11 = dot3_fma_asc(E[3],E[4],E[5], T[3],T[4],T[5]);
    float d22 = dot3_fma_asc(E[6],E[7],E[8], T[6],T[7],T[8]);

    float tr = add_rn(add_rn(d00, d11), d22);    // (d00+d11)+d22
    float ca = 0.5f * sub_rn(tr, 1.0f);          // *0.5 exact
    constexpr float HI = 1.0f - 1e-7f;           // 0x3F7FFFFE == np bound
    ca = fminf(fmaxf(ca, -HI), HI);
    float angle = acosf(ca);
    float sa    = sinf(angle);
    // clamp => angle >= ~4.9e-4 > 1e-6: reference Taylor branch is dead
    float coef = (0.5f * angle) / sa;

    // ---- vee path: same chain for consistency ----
    float d01 = dot3_fma_asc(E[0],E[1],E[2], T[3],T[4],T[5]);
    float d02 = dot3_fma_asc(E[0],E[1],E[2], T[6],T[7],T[8]);
    float d10 = dot3_fma_asc(E[3],E[4],E[5], T[0],T[1],T[2]);
    float d12 = dot3_fma_asc(E[3],E[4],E[5], T[6],T[7],T[8]);
    float d20 = dot3_fma_asc(E[6],E[7],E[8], T[0],T[1],T[2]);
    float d21 = dot3_fma_asc(E[6],E[7],E[8], T[3],T[4],T[5]);

    float r0 = coef * sub_rn(d21, d12);
    float r1 = coef * sub_rn(d02, d20);
    float r2 = coef * sub_rn(d10, d01);

    // ---- well-conditioned tail: plain f32 ----
    float w = 0.5f * (r0 * ((R[0]*r0 + R[1]*r1) + R[2]*r2) +
                      r1 * ((R[3]*r0 + R[4]*r1) + R[5]*r2) +
                      r2 * ((R[6]*r0 + R[7]*r1) + R[8]*r2));

    float det = R[0] * (R[4]*R[8] - R[5]*R[7])
              - R[1] * (R[3]*R[8] - R[5]*R[6])
              + R[2] * (R[3]*R[7] - R[4]*R[6]);

    return w - 0.5f * logf(det);
}

// Round-5 experiment: minimize VMEM instruction count per element.
// Evidence: 78 us/dispatch invariant to occupancy, data source, pipelining,
// and LDS-vs-direct structure; VALUBusy 9-11% matches the actual VALU work
// at full clock => waves wait ~90% on the vector-memory request path, whose
// load is measured in ISSUED VMEM INSTRUCTIONS (source-invariant).
// This kernel: 4 elements/thread. 4*36 B = 144 B per array = exactly 9
// aligned dwordx4 loads; 27 loads + 1 float4 store per 4 elements
// = 7 VMEM/element vs 10 in all prior rounds (1.43x fewer).
__global__ __launch_bounds__(BLK, 2) void so3_nll_kernel(
    const float* __restrict__ C_est,
    const float* __restrict__ C_tgt,
    const float* __restrict__ Rinv,
    float* __restrict__ out,
    int B)
{
    const long long nquad_full = (long long)(B >> 2);   // full groups of 4
    const long long q = (long long)blockIdx.x * BLK + threadIdx.x;

    if (q < nquad_full) {
        // Byte base = q*144, multiple of 16 -> all loads aligned dwordx4.
        const float4* gE = reinterpret_cast<const float4*>(C_est) + q * 9;
        const float4* gT = reinterpret_cast<const float4*>(C_tgt) + q * 9;
        const float4* gR = reinterpret_cast<const float4*>(Rinv)  + q * 9;

        float e[36], t[36], rr[36];
        #pragma unroll
        for (int i = 0; i < 9; ++i) {
            *reinterpret_cast<float4*>(&e[4 * i])  = gE[i];
            *reinterpret_cast<float4*>(&t[4 * i])  = gT[i];
            *reinterpret_cast<float4*>(&rr[4 * i]) = gR[i];
        }

        float nll[4];
        #pragma unroll
        for (int k = 0; k < 4; ++k)
            nll[k] = so3_nll_elem(&e[9 * k], &t[9 * k], &rr[9 * k]);

        float4 o;
        o.x = nll[0]; o.y = nll[1]; o.z = nll[2]; o.w = nll[3];
        *reinterpret_cast<float4*>(out + q * 4) = o;   // byte 16q: aligned
    } else if (q == nquad_full) {
        // Tail elements (B % 4): at most 3, handled scalar by one thread.
        for (long long el = nquad_full * 4; el < (long long)B; ++el) {
            float E[9], T[9], R[9];
            const size_t base = (size_t)el * 9;
            #pragma unroll
            for (int j = 0; j < 9; ++j) {
                E[j] = C_est[base + j];
                T[j] = C_tgt[base + j];
                R[j] = Rinv [base + j];
            }
            out[el] = so3_nll_elem(E, T, R);
        }
    }
}

extern "C" void kernel_launch(void* const* d_in, const int* in_sizes, int n_in,
                              void* d_out, int out_size, void* d_ws, size_t ws_size,
                              hipStream_t stream) {
    const float* C_est = (const float*)d_in[0];
    const float* C_tgt = (const float*)d_in[1];
    const float* Rinv  = (const float*)d_in[2];
    float* out = (float*)d_out;

    const int B = in_sizes[0] / 9;
    const long long nquad_total = (B >> 2) + ((B & 3) ? 1 : 0);
    const int blocks = (int)((nquad_total + BLK - 1) / BLK);
    so3_nll_kernel<<<blocks, BLK, 0, stream>>>(C_est, C_tgt, Rinv, out, B);
}

// Round 7
// 205.640 us; speedup vs baseline: 1.0273x; 1.0273x over previous
//
#include <hip/hip_runtime.h>

constexpr int BLK = 256;

// Compiler-proof IEEE f32 rn ops (inline asm: no fusion/reassociation
// beyond what is written).
__device__ __forceinline__ float mul_rn(float a, float b) {
    float r; asm("v_mul_f32 %0, %1, %2" : "=v"(r) : "v"(a), "v"(b)); return r;
}
__device__ __forceinline__ float add_rn(float a, float b) {
    float r; asm("v_add_f32 %0, %1, %2" : "=v"(r) : "v"(a), "v"(b)); return r;
}
__device__ __forceinline__ float sub_rn(float a, float b) {
    float r; asm("v_sub_f32 %0, %1, %2" : "=v"(r) : "v"(a), "v"(b)); return r;
}
__device__ __forceinline__ float fma_rn(float a, float b, float c) {
    float r; asm("v_fma_f32 %0, %1, %2, %3"
                 : "=v"(r) : "v"(a), "v"(b), "v"(c)); return r;
}

// Ascending FMA chain from zero — matches the np/XLA-lowered dot rounding:
//   fma(a2,b2, fma(a1,b1, rn(a0*b0)))
// Do not reassociate; do not let the compiler contract it differently.
__device__ __forceinline__ float dot3_fma_asc(float a0, float a1, float a2,
                                              float b0, float b1, float b2) {
    return fma_rn(a2, b2, fma_rn(a1, b1, mul_rn(a0, b0)));
}

// 4-byte-aligned vector types so clang legally emits dwordx4/dwordx2 at
// the 36-B record stride (gfx950 global loads need only dword alignment).
typedef float __attribute__((ext_vector_type(4), aligned(4))) f32x4u;

// Round-6 discriminating experiment: NONTEMPORAL loads.
// Evidence recap: 5 structurally different kernels (LDS-staged, pipelined,
// persistent, elementwise, 4-elem/thread) all pin at 2.85-2.89 TB/s
// consumption; occupancy 31-70%, VGPR 24-64, VMEM count 7-10/elem all
// irrelevant. The 216 MB working set churns the 256 MB L3 (FETCH ~105 GB
// = half served by L3, half HBM). Two stories fit: (A) ~3.1 TB/s
// read-direction fabric cap (m13 copy: 6.29 TB/s bidirectional = 3.15 per
// direction; we are at 92% of it) => roofline; (B) L3 fill+evict churn
// throttles the stream => nt bypass wins big. The nt bit discriminates:
// FETCH_SIZE must jump to ~216 GB either way (proves nt engaged); only
// story B moves time.
__device__ __forceinline__ void load9_nt(const float* __restrict__ p, float* d) {
    f32x4u a = __builtin_nontemporal_load(reinterpret_cast<const f32x4u*>(p));
    f32x4u b = __builtin_nontemporal_load(reinterpret_cast<const f32x4u*>(p + 4));
    float  c = __builtin_nontemporal_load(p + 8);
    d[0] = a.x; d[1] = a.y; d[2] = a.z; d[3] = a.w;
    d[4] = b.x; d[5] = b.y; d[6] = b.z; d[7] = b.w;
    d[8] = c;
}

__global__ __launch_bounds__(BLK, 8) void so3_nll_kernel(
    const float* __restrict__ C_est,
    const float* __restrict__ C_tgt,
    const float* __restrict__ Rinv,
    float* __restrict__ out,
    int B)
{
    const int i_raw = blockIdx.x * BLK + threadIdx.x;
    const int i     = min(i_raw, B - 1);     // clamp: loads always in-bounds
    const size_t base = (size_t)i * 9;

    float E[9], T[9], R[9];
    load9_nt(C_est + base, E);
    load9_nt(C_tgt + base, T);
    load9_nt(Rinv  + base, R);

    // ---- chaotic chain: must match the np ref's f32 rounding ----
    float d00 = dot3_fma_asc(E[0],E[1],E[2], T[0],T[1],T[2]);
    float d11 = dot3_fma_asc(E[3],E[4],E[5], T[3],T[4],T[5]);
    float d22 = dot3_fma_asc(E[6],E[7],E[8], T[6],T[7],T[8]);

    float tr = add_rn(add_rn(d00, d11), d22);    // (d00+d11)+d22
    float ca = 0.5f * sub_rn(tr, 1.0f);          // *0.5 exact
    constexpr float HI = 1.0f - 1e-7f;           // 0x3F7FFFFE == np bound
    ca = fminf(fmaxf(ca, -HI), HI);
    float angle = acosf(ca);
    float sa    = sinf(angle);
    // clamp => angle >= ~4.9e-4 > 1e-6: reference Taylor branch is dead
    float coef = (0.5f * angle) / sa;

    // ---- vee path: same chain for consistency ----
    float d01 = dot3_fma_asc(E[0],E[1],E[2], T[3],T[4],T[5]);
    float d02 = dot3_fma_asc(E[0],E[1],E[2], T[6],T[7],T[8]);
    float d10 = dot3_fma_asc(E[3],E[4],E[5], T[0],T[1],T[2]);
    float d12 = dot3_fma_asc(E[3],E[4],E[5], T[6],T[7],T[8]);
    float d20 = dot3_fma_asc(E[6],E[7],E[8], T[0],T[1],T[2]);
    float d21 = dot3_fma_asc(E[6],E[7],E[8], T[3],T[4],T[5]);

    float r0 = coef * sub_rn(d21, d12);
    float r1 = coef * sub_rn(d02, d20);
    float r2 = coef * sub_rn(d10, d01);

    // ---- well-conditioned tail: plain f32 ----
    float w = 0.5f * (r0 * ((R[0]*r0 + R[1]*r1) + R[2]*r2) +
                      r1 * ((R[3]*r0 + R[4]*r1) + R[5]*r2) +
                      r2 * ((R[6]*r0 + R[7]*r1) + R[8]*r2));

    float det = R[0] * (R[4]*R[8] - R[5]*R[7])
              - R[1] * (R[3]*R[8] - R[5]*R[6])
              + R[2] * (R[3]*R[7] - R[4]*R[6]);

    if (i_raw < B)
        __builtin_nontemporal_store(w - 0.5f * logf(det), out + i_raw);
}

extern "C" void kernel_launch(void* const* d_in, const int* in_sizes, int n_in,
                              void* d_out, int out_size, void* d_ws, size_t ws_size,
                              hipStream_t stream) {
    const float* C_est = (const float*)d_in[0];
    const float* C_tgt = (const float*)d_in[1];
    const float* Rinv  = (const float*)d_in[2];
    float* out = (float*)d_out;

    const int B = in_sizes[0] / 9;
    const int blocks = (B + BLK - 1) / BLK;
    so3_nll_kernel<<<blocks, BLK, 0, stream>>>(C_est, C_tgt, Rinv, out, B);
}